// Round 11
// baseline (301.620 us; speedup 1.0000x reference)
//
#include <hip/hip_runtime.h>
#include <hip/hip_fp16.h>
#include <stdint.h>

#define N_NODES   100000
#define N_HALF    50000
#define N_EDGES   3200000
#define F_IN      128
#define F_HID     64
#define F_OUT     16

typedef _Float16 h2v __attribute__((ext_vector_type(2)));
typedef _Float16 h4v __attribute__((ext_vector_type(4)));
typedef _Float16 h8v __attribute__((ext_vector_type(8)));
typedef float    f4v __attribute__((ext_vector_type(4)));

// bucket params: 128-dst buckets
#define BSHIFT    7
#define BK        128                  // dst nodes per bucket
#define NBUCK     782                  // ceil(100000 / 128)
// deterministic partition: hist/scatter blocks
#define NBLK_H    1600
#define CHUNK_H   (N_EDGES / NBLK_H)   // 2000 edges per block
// bucket capacity: mean raw 4092, sigma ~64. 4992 = +14 sigma (no guard needed)
#define PSTRIDE   4992

// gemm1: 64-node block, 4 waves, mfma_f32_16x16x32_f16
#define G1_TM     64
#define G1_BLOCKS ((N_NODES + G1_TM - 1) / G1_TM)   // 1563

// ---- workspace layout (bytes) ----
#define OFF_RS       0                 // int[N]   rowstart
#define OFF_LEN      400000            // int[N]   c0 | c1<<16
#define OFF_DINV     800000            // float[N]
#define OFF_GCNT     1200000           // int[NBUCK]
#define OFF_CSR      1203200           // u16[NBUCK*PSTRIDE] = 7,807,488 B
#define OFF_HS1      9010688           // half[2][N][32] = 12,800,000 B (64B-aligned!)
#define OFF_OUT1A    21810688          // half[N][64] partials (64B-aligned - R10: saved 9us in agg1)
#define OFF_OUT1B    34610688          // half[N][64] partials
#define OFF_HS2      47410688          // half[N][16]
#define OFF_PAIRS    OFF_OUT1A         // uint[NBUCK*PSTRIDE] = 15,614,976 B, ends 37,425,664
#define OFF_CNT      37425664          // int[NBLK_H*NBUCK] = 5,004,800 B (in out1b; dead before agg1)
#define OFF_OFFT     42430464          // int[NBUCK*NBLK_H] = 5,004,800 B (tail overlaps hs2; dead before gemm2)
// total 50,610,688 bytes

__device__ __forceinline__ int detect_is64(const void* ei, int t) {
    __shared__ int is64s;
    if (t < 64) {
        const unsigned* u = (const unsigned*)ei;
        unsigned lo = u[2 * t], hi = u[2 * t + 1];
        int bad = (hi != 0u || lo >= 100000u) ? 1 : 0;
        unsigned long long mask = __ballot(bad);
        if (t == 0) is64s = (mask == 0ull);
    }
    __syncthreads();
    return is64s;
}

// ---- pass 1a: per-block dst histogram (NO atomics on global) ---------------
// Replaces the global-atomic reservation scheme: R6/R10 evidence pointed at
// 625K contended atomicAdds on ~49 L2 lines as the partition wall.
__global__ __launch_bounds__(256, 4) void k_hist(const void* __restrict__ ei,
                                                 int* __restrict__ cnt) {
    __shared__ int h[NBUCK];
    int t = threadIdx.x;
    int is64 = detect_is64(ei, t);
    for (int i = t; i < NBUCK; i += 256) h[i] = 0;
    __syncthreads();
    int shift = 2 + is64;
    const char* dp = (const char*)ei + ((size_t)N_EDGES << shift);
#define LD_IDX(p, e) __builtin_nontemporal_load((const unsigned*)((p) + ((size_t)(e) << shift)))
    int base = blockIdx.x * CHUNK_H;
    int i = t;
    for (; i + 768 < CHUNK_H; i += 1024) {
        unsigned d0 = LD_IDX(dp, base + i);
        unsigned d1 = LD_IDX(dp, base + i + 256);
        unsigned d2 = LD_IDX(dp, base + i + 512);
        unsigned d3 = LD_IDX(dp, base + i + 768);
        atomicAdd(&h[d0 >> BSHIFT], 1);
        atomicAdd(&h[d1 >> BSHIFT], 1);
        atomicAdd(&h[d2 >> BSHIFT], 1);
        atomicAdd(&h[d3 >> BSHIFT], 1);
    }
    for (; i < CHUNK_H; i += 256) {
        unsigned d = LD_IDX(dp, base + i);
        atomicAdd(&h[d >> BSHIFT], 1);
    }
#undef LD_IDX
    __syncthreads();
    int* dst = cnt + (size_t)blockIdx.x * NBUCK;
    for (int i2 = t; i2 < NBUCK; i2 += 256) dst[i2] = h[i2];
}

// ---- pass 1b: per-bucket scan of per-block counts -> exact offsets ---------
// One block per bucket: scan cnt[0..1600][b], write offT[b][blk] and gcnt[b].
__global__ __launch_bounds__(256) void k_offs(const int* __restrict__ cnt,
                                              int* __restrict__ offT,
                                              int* __restrict__ gcnt) {
    __shared__ int v[1792];            // 1600 padded to 256*7
    __shared__ int ts[256];
    int b = blockIdx.x, t = threadIdx.x;
    for (int i = t; i < 1792; i += 256)
        v[i] = (i < NBLK_H) ? cnt[(size_t)i * NBUCK + b] : 0;
    __syncthreads();
    int s = 0;
#pragma unroll
    for (int i = 0; i < 7; ++i) s += v[t * 7 + i];
    ts[t] = s;
    __syncthreads();
    for (int off = 1; off < 256; off <<= 1) {
        int add = (t >= off) ? ts[t - off] : 0;
        __syncthreads();
        ts[t] += add;
        __syncthreads();
    }
    int run = (t > 0) ? ts[t - 1] : 0;     // exclusive prefix of this thread's 7
    int base = b * PSTRIDE;
    int* od = offT + (size_t)b * NBLK_H;
#pragma unroll
    for (int i = 0; i < 7; ++i) {
        int idx = t * 7 + i;
        if (idx < NBLK_H) od[idx] = base + run;
        run += v[t * 7 + i];
    }
    if (t == 255) gcnt[b] = ts[255];
}

// ---- pass 1c: scatter edges into exact bucket positions (LDS cur only) -----
// Re-reads the edge list (extra 25.6MB stream ~ 4us) in exchange for: no LDS
// stash (3KB LDS -> 6 blocks/CU), no global atomics, deterministic packing.
__global__ __launch_bounds__(256, 4) void k_scatter(const void* __restrict__ ei,
                                                    const int* __restrict__ offT,
                                                    unsigned* __restrict__ pairs) {
    __shared__ int cur[NBUCK];
    int t = threadIdx.x;
    int is64 = detect_is64(ei, t);
    int blk = blockIdx.x;
    for (int i = t; i < NBUCK; i += 256)
        cur[i] = offT[(size_t)i * NBLK_H + blk];
    __syncthreads();
    int shift = 2 + is64;
    const char* sp = (const char*)ei;
    const char* dp = sp + ((size_t)N_EDGES << shift);
#define LD_IDX(p, e) __builtin_nontemporal_load((const unsigned*)((p) + ((size_t)(e) << shift)))
    int base = blk * CHUNK_H;
    int i = t;
    for (; i + 768 < CHUNK_H; i += 1024) {
        int e0 = base + i, e1 = e0 + 256, e2 = e0 + 512, e3 = e0 + 768;
        unsigned s0 = LD_IDX(sp, e0), s1 = LD_IDX(sp, e1);
        unsigned s2 = LD_IDX(sp, e2), s3 = LD_IDX(sp, e3);
        unsigned d0 = LD_IDX(dp, e0), d1 = LD_IDX(dp, e1);
        unsigned d2 = LD_IDX(dp, e2), d3 = LD_IDX(dp, e3);
        int p0 = atomicAdd(&cur[d0 >> BSHIFT], 1);
        int p1 = atomicAdd(&cur[d1 >> BSHIFT], 1);
        int p2 = atomicAdd(&cur[d2 >> BSHIFT], 1);
        int p3 = atomicAdd(&cur[d3 >> BSHIFT], 1);
        pairs[p0] = (s0 << BSHIFT) | (d0 & (BK - 1u));
        pairs[p1] = (s1 << BSHIFT) | (d1 & (BK - 1u));
        pairs[p2] = (s2 << BSHIFT) | (d2 & (BK - 1u));
        pairs[p3] = (s3 << BSHIFT) | (d3 & (BK - 1u));
    }
    for (; i < CHUNK_H; i += 256) {
        unsigned s = LD_IDX(sp, base + i);
        unsigned d = LD_IDX(dp, base + i);
        int p = atomicAdd(&cur[d >> BSHIFT], 1);
        pairs[p] = (s << BSHIFT) | (d & (BK - 1u));
    }
#undef LD_IDX
}

// ---- pass 2: per-bucket count/scan/place, split by src-half ----------------
// Per node: sub-row 0 (src<50000) then sub-row 1, each start 4-entry aligned.
// Entries u16 half-local src. Bucket pairs stashed in LDS during count pass;
// csr image streamed out as coalesced 16B stores. LDS 32.5KB, grid 782=3/CU.
__global__ __launch_bounds__(512) void k_build(const unsigned* __restrict__ pairs,
                                               const int* __restrict__ gcnt,
                                               int* __restrict__ rowstart,
                                               int* __restrict__ lens,
                                               float* __restrict__ dinv,
                                               unsigned short* __restrict__ csr) {
    __shared__ unsigned prS[PSTRIDE];            // 19,968 B
    __shared__ unsigned short csrS[PSTRIDE];     //  9,984 B
    __shared__ int c0S[BK], c1S[BK], scanS[BK], pos0[BK], pos1[BK];
    __shared__ int totpadS;
    int b = blockIdx.x, t = threadIdx.x;
    if (t < BK) { c0S[t] = 0; c1S[t] = 0; }
    __syncthreads();
    int tot = gcnt[b]; if (tot > PSTRIDE) tot = PSTRIDE;
    int base = b * PSTRIDE;
    for (int i = t; i < tot; i += 512) {
        unsigned pr = __builtin_nontemporal_load(pairs + base + i);
        prS[i] = pr;
        if ((pr >> BSHIFT) < (unsigned)N_HALF) atomicAdd(&c0S[pr & (BK - 1u)], 1);
        else                                   atomicAdd(&c1S[pr & (BK - 1u)], 1);
    }
    __syncthreads();
    int tpad = 0, p0a = 0;
    if (t < BK) {
        p0a = (c0S[t] + 3) & ~3;
        tpad = p0a + ((c1S[t] + 3) & ~3);
        scanS[t] = tpad;
    }
    __syncthreads();
    for (int off = 1; off < BK; off <<= 1) {
        int add = 0;
        if (t < BK && t >= off) add = scanS[t - off];
        __syncthreads();
        if (t < BK) scanS[t] += add;
        __syncthreads();
    }
    if (t < BK) {
        int rs = scanS[t] - tpad;          // exclusive scan, LOCAL, 4-aligned
        pos0[t] = rs;
        pos1[t] = rs + p0a;
        int d = (b << BSHIFT) + t;
        if (d < N_NODES) {
            rowstart[d] = base + rs;
            lens[d] = c0S[t] | (c1S[t] << 16);
            dinv[d] = rsqrtf((float)(c0S[t] + c1S[t]) + 1.0f);
        }
        if (t == BK - 1) totpadS = scanS[BK - 1];
    }
    __syncthreads();
    for (int i = t; i < tot; i += 512) {
        unsigned pr = prS[i];
        unsigned s = pr >> BSHIFT;
        int d = pr & (BK - 1u);
        if (s < (unsigned)N_HALF) {
            int p = atomicAdd(&pos0[d], 1);
            csrS[p] = (unsigned short)s;
        } else {
            int p = atomicAdd(&pos1[d], 1);
            csrS[p] = (unsigned short)(s - N_HALF);
        }
    }
    __syncthreads();
    int nchunk = (totpadS + 7) >> 3;       // 8 u16 per 16B chunk
    uint4* dst = (uint4*)(csr + base);     // base*2 = b*9984, 16B-multiple
    const uint4* srcp = (const uint4*)csrS;
    for (int i = t; i < nchunk; i += 512) dst[i] = srcp[i];
}

// ---- GEMM1 (MFMA fp16-in/fp32-acc): hs1[chunk32][node][32] = (x@W1)*dinv ---
__global__ __launch_bounds__(256, 4) void k_gemm1(const float* __restrict__ x,
                                                  const float* __restrict__ W1,
                                                  const float* __restrict__ dinv,
                                                  __half* __restrict__ hs1) {
    __shared__ _Float16 W1s[F_IN * F_HID];   // 16 KB, fragment-order
    int t = threadIdx.x;
    for (int idx = t; idx < F_IN * F_HID; idx += 256) {
        int k = idx >> 6, n = idx & 63;
        float v = W1[idx];
        int kc = k >> 5, ko = (k >> 3) & 3, j = k & 7;
        int nt = n >> 4, c = n & 15;
        W1s[((kc * 4 + ko) * 4 + nt) * 128 + c * 8 + j] = (_Float16)v;
    }
    __syncthreads();
    int w = t >> 6, l = t & 63;
    int lm = l & 15, lk = l >> 4;
    int nblock = blockIdx.x * G1_TM;
    int anode = nblock + w * 16 + lm;
    int anodec = anode < N_NODES ? anode : N_NODES - 1;
    f4v acc[4] = {};
    const h8v* Bp = (const h8v*)W1s;
#pragma unroll
    for (int kc = 0; kc < 4; ++kc) {
        const f4v* src = (const f4v*)(x + (size_t)anodec * F_IN + kc * 32 + lk * 8);
        f4v v0 = __builtin_nontemporal_load(src);
        f4v v1 = __builtin_nontemporal_load(src + 1);
        h8v a;
#pragma unroll
        for (int i = 0; i < 4; ++i) {
            a[i]     = (_Float16)v0[i];
            a[i + 4] = (_Float16)v1[i];
        }
#pragma unroll
        for (int nt = 0; nt < 4; ++nt) {
            h8v b = Bp[((kc * 4 + lk) * 4 + nt) * 16 + lm];
            acc[nt] = __builtin_amdgcn_mfma_f32_16x16x32_f16(a, b, acc[nt], 0, 0, 0);
        }
    }
#pragma unroll
    for (int r = 0; r < 4; ++r) {
        int node = nblock + w * 16 + lk * 4 + r;
        if (node < N_NODES) {
            float dv = dinv[node];
#pragma unroll
            for (int nt = 0; nt < 4; ++nt) {
                float val = acc[nt][r] * dv;
                hs1[((size_t)(nt >> 1) * N_NODES + node) * 32 + (nt & 1) * 16 + lm] =
                    __float2half(val);
            }
        }
    }
}

// ---- aggregate layer 1: 4 XCD-pinned (chunk x src-half) passes -------------
// Rate = per-CU L1 miss-parallelism wall (~0.19 sectors/cy/CU: ~32 in flight
// x ~175cy L2 latency). 64B-aligned out rows (R10) cut WRITE RMW: 65.8->56.4.
__global__ __launch_bounds__(256) void k_agg1(const __half* __restrict__ hs1,
                                              const unsigned short* __restrict__ csr,
                                              const int* __restrict__ rowstart,
                                              const int* __restrict__ lens,
                                              __half* __restrict__ out1a,
                                              __half* __restrict__ out1b) {
    int bid = blockIdx.x;            // grid = 12500
    int combo = bid & 3;
    int chunk = combo & 1, half = combo >> 1;
    int nb = bid >> 2;               // 0..3124
    int w = threadIdx.x >> 6, lane = threadIdx.x & 63;
    int slot = lane >> 3, fp = lane & 7;
    int n = nb * 32 + w * 8 + slot;  // 3125*32 = 100000 exact
    const char* T = (const char*)hs1
                  + (size_t)chunk * ((size_t)N_NODES * 64)
                  + (size_t)half * ((size_t)N_HALF * 64);
    unsigned fo = fp * 8u;
    int rs = rowstart[n];
    int L = lens[n];
    int c0 = L & 0xffff;
    int start = half ? (rs + ((c0 + 3) & ~3)) : rs;
    int c = half ? (L >> 16) : c0;
    h4v a0 = {(_Float16)0.f, (_Float16)0.f, (_Float16)0.f, (_Float16)0.f};
    h4v a1 = a0, a2 = a0, a3 = a0;
    const unsigned long long* Q = (const unsigned long long*)csr;
    int q0 = start >> 2;
    int nq = c >> 2;
#define ROW1(idx) (*(const h4v*)(T + (unsigned)(idx) * 64u + fo))
    int q = 0;
    unsigned long long ea = 0ull, eb = 0ull;
    if (q + 2 <= nq) { ea = Q[q0]; eb = Q[q0 + 1]; }
    while (q + 2 <= nq) {
        unsigned long long ca = ea, cb = eb;
        q += 2;
        if (q + 2 <= nq) { ea = Q[q0 + q]; eb = Q[q0 + q + 1]; }
        h4v t0 = ROW1(ca & 0xffffu);
        h4v t1 = ROW1((ca >> 16) & 0xffffu);
        h4v t2 = ROW1((ca >> 32) & 0xffffu);
        h4v t3 = ROW1(ca >> 48);
        h4v t4 = ROW1(cb & 0xffffu);
        h4v t5 = ROW1((cb >> 16) & 0xffffu);
        h4v t6 = ROW1((cb >> 32) & 0xffffu);
        h4v t7 = ROW1(cb >> 48);
        a0 += t0; a1 += t1; a2 += t2; a3 += t3;
        a0 += t4; a1 += t5; a2 += t6; a3 += t7;
    }
    if (q < nq) {
        unsigned long long e = Q[q0 + q];
        a0 += ROW1(e & 0xffffu);
        a1 += ROW1((e >> 16) & 0xffffu);
        a2 += ROW1((e >> 32) & 0xffffu);
        a3 += ROW1(e >> 48);
    }
    for (int j = start + (nq << 2); j < start + c; ++j)
        a0 += ROW1(csr[j]);
    if ((n >= N_HALF) == (half != 0))
        a1 += ROW1(n - half * N_HALF);
#undef ROW1
    float s0 = ((float)a0[0] + (float)a1[0]) + ((float)a2[0] + (float)a3[0]);
    float s1 = ((float)a0[1] + (float)a1[1]) + ((float)a2[1] + (float)a3[1]);
    float s2 = ((float)a0[2] + (float)a1[2]) + ((float)a2[2] + (float)a3[2]);
    float s3 = ((float)a0[3] + (float)a1[3]) + ((float)a2[3] + (float)a3[3]);
    union { __half2 h[2]; float2 f; } u;
    u.h[0] = __floats2half2_rn(s0, s1);
    u.h[1] = __floats2half2_rn(s2, s3);
    __half* dst = (half ? out1b : out1a) + (size_t)n * F_HID + chunk * 32 + fp * 4;
    *(float2*)dst = u.f;
}

// ---- GEMM2: hs2 = (relu(dinv*(pa+pb)+b1) @ W2) * dinv, fp16 ---------------
__global__ __launch_bounds__(256) void k_gemm2(const __half* __restrict__ out1a,
                                               const __half* __restrict__ out1b,
                                               const float* __restrict__ W2,
                                               const float* __restrict__ dinv,
                                               const float* __restrict__ b1,
                                               __half* __restrict__ hs2) {
    __shared__ float ws[F_HID * F_OUT];
    __shared__ float b1s[F_HID];
    int t = threadIdx.x;
    ((float4*)ws)[t] = ((const float4*)W2)[t];
    if (t < 16) ((float4*)b1s)[t] = ((const float4*)b1)[t];
    __syncthreads();
    int tid = blockIdx.x * 256 + t;
    int n = tid >> 2;
    if (n >= N_NODES) return;
    int cq = (tid & 3) << 2;
    float dv = dinv[n];
    const h2v* A = (const h2v*)(out1a + (size_t)n * F_HID);
    const h2v* B = (const h2v*)(out1b + (size_t)n * F_HID);
    float4 acc = make_float4(0.f, 0.f, 0.f, 0.f);
#pragma unroll 4
    for (int k4 = 0; k4 < 16; ++k4) {
        h2v pa0 = A[k4 * 2], pa1 = A[k4 * 2 + 1];
        h2v pb0 = B[k4 * 2], pb1 = B[k4 * 2 + 1];
        float h0 = fmaxf(dv * ((float)pa0.x + (float)pb0.x) + b1s[k4 * 4 + 0], 0.f);
        float h1 = fmaxf(dv * ((float)pa0.y + (float)pb0.y) + b1s[k4 * 4 + 1], 0.f);
        float h2 = fmaxf(dv * ((float)pa1.x + (float)pb1.x) + b1s[k4 * 4 + 2], 0.f);
        float h3 = fmaxf(dv * ((float)pa1.y + (float)pb1.y) + b1s[k4 * 4 + 3], 0.f);
        float4 w0 = *(const float4*)(ws + (k4 * 4 + 0) * F_OUT + cq);
        float4 w1 = *(const float4*)(ws + (k4 * 4 + 1) * F_OUT + cq);
        float4 w2 = *(const float4*)(ws + (k4 * 4 + 2) * F_OUT + cq);
        float4 w3 = *(const float4*)(ws + (k4 * 4 + 3) * F_OUT + cq);
        acc.x += h0 * w0.x + h1 * w1.x + h2 * w2.x + h3 * w3.x;
        acc.y += h0 * w0.y + h1 * w1.y + h2 * w2.y + h3 * w3.y;
        acc.z += h0 * w0.z + h1 * w1.z + h2 * w2.z + h3 * w3.z;
        acc.w += h0 * w0.w + h1 * w1.w + h2 * w2.w + h3 * w3.w;
    }
    union { __half2 h2x[2]; float2 f; } u;
    u.h2x[0] = __floats2half2_rn(acc.x * dv, acc.y * dv);
    u.h2x[1] = __floats2half2_rn(acc.z * dv, acc.w * dv);
    *(float2*)(hs2 + (size_t)n * F_OUT + cq) = u.f;
}

// ---- aggregate layer 2: single pass (3.2MB table L2-wide), split sub-rows --
__global__ __launch_bounds__(128) void k_agg2(const __half* __restrict__ hs2,
                                              const unsigned short* __restrict__ csr,
                                              const int* __restrict__ rowstart,
                                              const int* __restrict__ lens,
                                              const float* __restrict__ dinv,
                                              const float* __restrict__ b2,
                                              float* __restrict__ out) {
    int w = threadIdx.x >> 6, lane = threadIdx.x & 63;
    int slot = lane >> 2, fp = lane & 3;
    int n = blockIdx.x * 32 + w * 16 + slot;   // grid = 3125, exact
    unsigned fo = fp * 8u;
    int rs = rowstart[n];
    int L = lens[n];
    int c0 = L & 0xffff, c1 = L >> 16;
    const unsigned long long* Q = (const unsigned long long*)csr;
    h4v a0 = {(_Float16)0.f, (_Float16)0.f, (_Float16)0.f, (_Float16)0.f};
    h4v a1 = a0, a2 = a0, a3 = a0;
#pragma unroll
    for (int half = 0; half < 2; ++half) {
        const char* T = (const char*)hs2 + (size_t)half * ((size_t)N_HALF * 32);
        int start = half ? (rs + ((c0 + 3) & ~3)) : rs;
        int c = half ? c1 : c0;
        int q0 = start >> 2;
        int nq = c >> 2;
#define ROW2(idx) (*(const h4v*)(T + (unsigned)(idx) * 32u + fo))
        int q = 0;
        unsigned long long ea = 0ull, eb = 0ull;
        if (q + 2 <= nq) { ea = Q[q0]; eb = Q[q0 + 1]; }
        while (q + 2 <= nq) {
            unsigned long long ca = ea, cb = eb;
            q += 2;
            if (q + 2 <= nq) { ea = Q[q0 + q]; eb = Q[q0 + q + 1]; }
            h4v t0 = ROW2(ca & 0xffffu);
            h4v t1 = ROW2((ca >> 16) & 0xffffu);
            h4v t2 = ROW2((ca >> 32) & 0xffffu);
            h4v t3 = ROW2(ca >> 48);
            h4v t4 = ROW2(cb & 0xffffu);
            h4v t5 = ROW2((cb >> 16) & 0xffffu);
            h4v t6 = ROW2((cb >> 32) & 0xffffu);
            h4v t7 = ROW2(cb >> 48);
            a0 += t0; a1 += t1; a2 += t2; a3 += t3;
            a0 += t4; a1 += t5; a2 += t6; a3 += t7;
        }
        if (q < nq) {
            unsigned long long e = Q[q0 + q];
            a0 += ROW2(e & 0xffffu);
            a1 += ROW2((e >> 16) & 0xffffu);
            a2 += ROW2((e >> 32) & 0xffffu);
            a3 += ROW2(e >> 48);
        }
        for (int j = start + (nq << 2); j < start + c; ++j)
            a0 += ROW2(csr[j]);
#undef ROW2
    }
    // self
    a1 += *(const h4v*)((const char*)hs2 + (unsigned)n * 32u + fo);
    float dv = dinv[n];
    int fb = fp * 4;
    float s0 = ((float)a0[0] + (float)a1[0]) + ((float)a2[0] + (float)a3[0]);
    float s1 = ((float)a0[1] + (float)a1[1]) + ((float)a2[1] + (float)a3[1]);
    float s2 = ((float)a0[2] + (float)a1[2]) + ((float)a2[2] + (float)a3[2]);
    float s3 = ((float)a0[3] + (float)a1[3]) + ((float)a2[3] + (float)a3[3]);
    float ox0 = dv * s0 + b2[fb + 0];
    float ox1 = dv * s1 + b2[fb + 1];
    float ox2 = dv * s2 + b2[fb + 2];
    float ox3 = dv * s3 + b2[fb + 3];
    float4* dst = (float4*)(out + (size_t)n * F_OUT + fb);
    *dst = make_float4(ox0, ox1, ox2, ox3);
}

extern "C" void kernel_launch(void* const* d_in, const int* in_sizes, int n_in,
                              void* d_out, int out_size, void* d_ws, size_t ws_size,
                              hipStream_t stream) {
    const float* x  = (const float*)d_in[0];
    const void*  ei = d_in[1];
    const float* W1 = (const float*)d_in[2];
    const float* b1 = (const float*)d_in[3];
    const float* W2 = (const float*)d_in[4];
    const float* b2 = (const float*)d_in[5];
    float* out = (float*)d_out;

    char* ws = (char*)d_ws;
    int*            rowstart = (int*)(ws + OFF_RS);
    int*            lens     = (int*)(ws + OFF_LEN);
    float*          dinv     = (float*)(ws + OFF_DINV);
    int*            gcnt     = (int*)(ws + OFF_GCNT);
    unsigned short* csr      = (unsigned short*)(ws + OFF_CSR);
    __half*         hs1      = (__half*)(ws + OFF_HS1);
    __half*         out1a    = (__half*)(ws + OFF_OUT1A);
    __half*         out1b    = (__half*)(ws + OFF_OUT1B);
    __half*         hs2      = (__half*)(ws + OFF_HS2);
    unsigned*       pairs    = (unsigned*)(ws + OFF_PAIRS);
    int*            cnt      = (int*)(ws + OFF_CNT);
    int*            offT     = (int*)(ws + OFF_OFFT);

    // edge prep: deterministic (atomic-free) partition + fused count/scan/place
    k_hist   <<<NBLK_H, 256, 0, stream>>>(ei, cnt);
    k_offs   <<<NBUCK, 256, 0, stream>>>(cnt, offT, gcnt);
    k_scatter<<<NBLK_H, 256, 0, stream>>>(ei, offT, pairs);
    k_build  <<<NBUCK, 512, 0, stream>>>(pairs, gcnt, rowstart, lens, dinv, csr);

    // GCN layers
    k_gemm1<<<G1_BLOCKS, 256, 0, stream>>>(x, W1, dinv, hs1);
    k_agg1 <<<12500, 256, 0, stream>>>(hs1, csr, rowstart, lens, out1a, out1b);
    k_gemm2<<<(N_NODES * 4 + 255) / 256, 256, 0, stream>>>(out1a, out1b, W2, dinv, b1, hs2);
    k_agg2 <<<3125, 128, 0, stream>>>(hs2, csr, rowstart, lens, dinv, b2, out);
}

// Round 12
// 254.421 us; speedup vs baseline: 1.1855x; 1.1855x over previous
//
#include <hip/hip_runtime.h>
#include <hip/hip_fp16.h>
#include <stdint.h>

#define N_NODES   100000
#define N_HALF    50000
#define N_EDGES   3200000
#define F_IN      128
#define F_HID     64
#define F_OUT     16

typedef _Float16 h2v __attribute__((ext_vector_type(2)));
typedef _Float16 h4v __attribute__((ext_vector_type(4)));
typedef _Float16 h8v __attribute__((ext_vector_type(8)));
typedef float    f4v __attribute__((ext_vector_type(4)));

// bucket params: 128-dst buckets
#define BSHIFT    7
#define BK        128                  // dst nodes per bucket
#define NBUCK     782                  // ceil(100000 / 128)
// partition: NBLK_P x NBUCK x 64B = scatter write-sector amplification
// (R11 measured: 1600x782 -> 83MB HBM writes for 12.8MB of pairs).
// 400x782x64 = 20MB. Stash packed to 6B/edge so CHUNK=8000 fits LDS.
#define NBLK_P    400
#define CHUNK_E   (N_EDGES / NBLK_P)   // 8000 edges per block
// bucket capacity: mean raw 4092, sigma ~64. 4992 = +14 sigma.
#define PSTRIDE   4992

// gemm1: 64-node block, 4 waves, mfma_f32_16x16x32_f16
#define G1_TM     64
#define G1_BLOCKS ((N_NODES + G1_TM - 1) / G1_TM)   // 1563

// ---- workspace layout (bytes) ----
#define OFF_RS       0                 // int[N]   rowstart
#define OFF_LEN      400000            // int[N]   c0 | c1<<16
#define OFF_DINV     800000            // float[N]
#define OFF_GCNT     1200000           // int[NBUCK]
#define OFF_CSR      1203200           // u16[NBUCK*PSTRIDE] = 7,807,488 B
#define OFF_HS1      9010688           // half[2][N][32] = 12,800,000 B (64B-aligned!)
#define OFF_OUT1A    21810688          // half[N][64] partials (64B-aligned - R10: saved 9us in agg1)
#define OFF_OUT1B    34610688          // half[N][64] partials
#define OFF_HS2      47410688          // half[N][16]
#define OFF_PAIRS    OFF_OUT1A         // uint[NBUCK*PSTRIDE] = 15,614,976 B, aliases out1a/b
// total 50,610,688 bytes

// ---- pass 1: partition edges into fixed-capacity bucket regions ------------
// Single edge read; (pair,bucket) stashed in LDS (6B/edge) during histogram,
// scattered from LDS after a per-bucket global reservation.
// Write traffic = NBLK_P x NBUCK x 64B sector-touches (R11's lesson) -> 20MB.
// __launch_bounds__ guard: R4 showed the allocator can go to 8 VGPRs and
// serialize all memory ops if allowed to chase occupancy.
__global__ __launch_bounds__(256, 2) void k_partition(const void* __restrict__ ei,
                                                      int* __restrict__ gcnt,
                                                      unsigned* __restrict__ pairs) {
    __shared__ unsigned stp[CHUNK_E];        // 32,000 B packed pair
    __shared__ unsigned short stb[CHUNK_E];  // 16,000 B bucket id
    __shared__ int h[NBUCK];                 //  3,128 B
    __shared__ int cur[NBUCK];               //  3,128 B   total 54,256 B
    __shared__ int is64s;
    int t = threadIdx.x;
    if (t < 64) {
        const unsigned* u = (const unsigned*)ei;
        unsigned lo = u[2 * t], hi = u[2 * t + 1];
        int bad = (hi != 0u || lo >= 100000u) ? 1 : 0;
        unsigned long long mask = __ballot(bad);
        if (t == 0) is64s = (mask == 0ull);
    }
    for (int i = t; i < NBUCK; i += 256) h[i] = 0;
    __syncthreads();
    int shift = 2 + is64s;
    const char* sp = (const char*)ei;
    const char* dp = sp + ((size_t)N_EDGES << shift);
#define LD_IDX(p, e) __builtin_nontemporal_load((const unsigned*)((p) + ((size_t)(e) << shift)))
    int base = blockIdx.x * CHUNK_E;
    int i = t;
    for (; i + 768 < CHUNK_E; i += 1024) {
        int e0 = base + i, e1 = e0 + 256, e2 = e0 + 512, e3 = e0 + 768;
        unsigned s0 = LD_IDX(sp, e0), s1 = LD_IDX(sp, e1);
        unsigned s2 = LD_IDX(sp, e2), s3 = LD_IDX(sp, e3);
        unsigned d0 = LD_IDX(dp, e0), d1 = LD_IDX(dp, e1);
        unsigned d2 = LD_IDX(dp, e2), d3 = LD_IDX(dp, e3);
        stp[i]       = (s0 << BSHIFT) | (d0 & (BK - 1u));
        stp[i + 256] = (s1 << BSHIFT) | (d1 & (BK - 1u));
        stp[i + 512] = (s2 << BSHIFT) | (d2 & (BK - 1u));
        stp[i + 768] = (s3 << BSHIFT) | (d3 & (BK - 1u));
        stb[i]       = (unsigned short)(d0 >> BSHIFT);
        stb[i + 256] = (unsigned short)(d1 >> BSHIFT);
        stb[i + 512] = (unsigned short)(d2 >> BSHIFT);
        stb[i + 768] = (unsigned short)(d3 >> BSHIFT);
        atomicAdd(&h[d0 >> BSHIFT], 1);
        atomicAdd(&h[d1 >> BSHIFT], 1);
        atomicAdd(&h[d2 >> BSHIFT], 1);
        atomicAdd(&h[d3 >> BSHIFT], 1);
    }
    for (; i < CHUNK_E; i += 256) {
        unsigned s = LD_IDX(sp, base + i);
        unsigned d = LD_IDX(dp, base + i);
        stp[i] = (s << BSHIFT) | (d & (BK - 1u));
        stb[i] = (unsigned short)(d >> BSHIFT);
        atomicAdd(&h[d >> BSHIFT], 1);
    }
#undef LD_IDX
    __syncthreads();
    for (int j = t; j < NBUCK; j += 256) {
        int c = h[j];
        cur[j] = c ? atomicAdd(&gcnt[j], c) : 0;
    }
    __syncthreads();
    i = t;
    for (; i + 768 < CHUNK_E; i += 1024) {
        unsigned p0v = stp[i],       p1v = stp[i + 256];
        unsigned p2v = stp[i + 512], p3v = stp[i + 768];
        int b0 = stb[i], b1 = stb[i + 256], b2 = stb[i + 512], b3 = stb[i + 768];
        int p0 = atomicAdd(&cur[b0], 1);
        int p1 = atomicAdd(&cur[b1], 1);
        int p2 = atomicAdd(&cur[b2], 1);
        int p3 = atomicAdd(&cur[b3], 1);
        if (p0 < PSTRIDE) pairs[b0 * PSTRIDE + p0] = p0v;
        if (p1 < PSTRIDE) pairs[b1 * PSTRIDE + p1] = p1v;
        if (p2 < PSTRIDE) pairs[b2 * PSTRIDE + p2] = p2v;
        if (p3 < PSTRIDE) pairs[b3 * PSTRIDE + p3] = p3v;
    }
    for (; i < CHUNK_E; i += 256) {
        int b = stb[i];
        int p = atomicAdd(&cur[b], 1);
        if (p < PSTRIDE) pairs[b * PSTRIDE + p] = stp[i];
    }
}

// ---- pass 2: per-bucket count/scan/place, split by src-half ----------------
// Per node: sub-row 0 (src<50000) then sub-row 1, each start 4-entry aligned.
// Entries u16 half-local src. Bucket pairs stashed in LDS during count pass;
// csr image streamed out as coalesced 16B stores. LDS 32.5KB, grid 782=3/CU.
__global__ __launch_bounds__(512) void k_build(const unsigned* __restrict__ pairs,
                                               const int* __restrict__ gcnt,
                                               int* __restrict__ rowstart,
                                               int* __restrict__ lens,
                                               float* __restrict__ dinv,
                                               unsigned short* __restrict__ csr) {
    __shared__ unsigned prS[PSTRIDE];            // 19,968 B
    __shared__ unsigned short csrS[PSTRIDE];     //  9,984 B
    __shared__ int c0S[BK], c1S[BK], scanS[BK], pos0[BK], pos1[BK];
    __shared__ int totpadS;
    int b = blockIdx.x, t = threadIdx.x;
    if (t < BK) { c0S[t] = 0; c1S[t] = 0; }
    __syncthreads();
    int tot = gcnt[b]; if (tot > PSTRIDE) tot = PSTRIDE;
    int base = b * PSTRIDE;
    for (int i = t; i < tot; i += 512) {
        unsigned pr = __builtin_nontemporal_load(pairs + base + i);
        prS[i] = pr;
        if ((pr >> BSHIFT) < (unsigned)N_HALF) atomicAdd(&c0S[pr & (BK - 1u)], 1);
        else                                   atomicAdd(&c1S[pr & (BK - 1u)], 1);
    }
    __syncthreads();
    int tpad = 0, p0a = 0;
    if (t < BK) {
        p0a = (c0S[t] + 3) & ~3;
        tpad = p0a + ((c1S[t] + 3) & ~3);
        scanS[t] = tpad;
    }
    __syncthreads();
    for (int off = 1; off < BK; off <<= 1) {
        int add = 0;
        if (t < BK && t >= off) add = scanS[t - off];
        __syncthreads();
        if (t < BK) scanS[t] += add;
        __syncthreads();
    }
    if (t < BK) {
        int rs = scanS[t] - tpad;          // exclusive scan, LOCAL, 4-aligned
        pos0[t] = rs;
        pos1[t] = rs + p0a;
        int d = (b << BSHIFT) + t;
        if (d < N_NODES) {
            rowstart[d] = base + rs;
            lens[d] = c0S[t] | (c1S[t] << 16);
            dinv[d] = rsqrtf((float)(c0S[t] + c1S[t]) + 1.0f);
        }
        if (t == BK - 1) totpadS = scanS[BK - 1];
    }
    __syncthreads();
    for (int i = t; i < tot; i += 512) {
        unsigned pr = prS[i];
        unsigned s = pr >> BSHIFT;
        int d = pr & (BK - 1u);
        if (s < (unsigned)N_HALF) {
            int p = atomicAdd(&pos0[d], 1);
            csrS[p] = (unsigned short)s;
        } else {
            int p = atomicAdd(&pos1[d], 1);
            csrS[p] = (unsigned short)(s - N_HALF);
        }
    }
    __syncthreads();
    int nchunk = (totpadS + 7) >> 3;       // 8 u16 per 16B chunk
    uint4* dst = (uint4*)(csr + base);     // base*2 = b*9984, 16B-multiple
    const uint4* srcp = (const uint4*)csrS;
    for (int i = t; i < nchunk; i += 512) dst[i] = srcp[i];
}

// ---- GEMM1 (MFMA fp16-in/fp32-acc): hs1[chunk32][node][32] = (x@W1)*dinv ---
__global__ __launch_bounds__(256, 4) void k_gemm1(const float* __restrict__ x,
                                                  const float* __restrict__ W1,
                                                  const float* __restrict__ dinv,
                                                  __half* __restrict__ hs1) {
    __shared__ _Float16 W1s[F_IN * F_HID];   // 16 KB, fragment-order
    int t = threadIdx.x;
    for (int idx = t; idx < F_IN * F_HID; idx += 256) {
        int k = idx >> 6, n = idx & 63;
        float v = W1[idx];
        int kc = k >> 5, ko = (k >> 3) & 3, j = k & 7;
        int nt = n >> 4, c = n & 15;
        W1s[((kc * 4 + ko) * 4 + nt) * 128 + c * 8 + j] = (_Float16)v;
    }
    __syncthreads();
    int w = t >> 6, l = t & 63;
    int lm = l & 15, lk = l >> 4;
    int nblock = blockIdx.x * G1_TM;
    int anode = nblock + w * 16 + lm;
    int anodec = anode < N_NODES ? anode : N_NODES - 1;
    f4v acc[4] = {};
    const h8v* Bp = (const h8v*)W1s;
#pragma unroll
    for (int kc = 0; kc < 4; ++kc) {
        const f4v* src = (const f4v*)(x + (size_t)anodec * F_IN + kc * 32 + lk * 8);
        f4v v0 = __builtin_nontemporal_load(src);
        f4v v1 = __builtin_nontemporal_load(src + 1);
        h8v a;
#pragma unroll
        for (int i = 0; i < 4; ++i) {
            a[i]     = (_Float16)v0[i];
            a[i + 4] = (_Float16)v1[i];
        }
#pragma unroll
        for (int nt = 0; nt < 4; ++nt) {
            h8v b = Bp[((kc * 4 + lk) * 4 + nt) * 16 + lm];
            acc[nt] = __builtin_amdgcn_mfma_f32_16x16x32_f16(a, b, acc[nt], 0, 0, 0);
        }
    }
#pragma unroll
    for (int r = 0; r < 4; ++r) {
        int node = nblock + w * 16 + lk * 4 + r;
        if (node < N_NODES) {
            float dv = dinv[node];
#pragma unroll
            for (int nt = 0; nt < 4; ++nt) {
                float val = acc[nt][r] * dv;
                hs1[((size_t)(nt >> 1) * N_NODES + node) * 32 + (nt & 1) * 16 + lm] =
                    __float2half(val);
            }
        }
    }
}

// ---- aggregate layer 1: 4 XCD-pinned (chunk x src-half) passes -------------
// Rate = per-CU L1 miss-parallelism wall (~0.19 sectors/cy/CU: ~32 in flight
// x ~175cy L2 latency). 64B-aligned out rows (R10) cut WRITE RMW: 65.8->56.4.
__global__ __launch_bounds__(256) void k_agg1(const __half* __restrict__ hs1,
                                              const unsigned short* __restrict__ csr,
                                              const int* __restrict__ rowstart,
                                              const int* __restrict__ lens,
                                              __half* __restrict__ out1a,
                                              __half* __restrict__ out1b) {
    int bid = blockIdx.x;            // grid = 12500
    int combo = bid & 3;
    int chunk = combo & 1, half = combo >> 1;
    int nb = bid >> 2;               // 0..3124
    int w = threadIdx.x >> 6, lane = threadIdx.x & 63;
    int slot = lane >> 3, fp = lane & 7;
    int n = nb * 32 + w * 8 + slot;  // 3125*32 = 100000 exact
    const char* T = (const char*)hs1
                  + (size_t)chunk * ((size_t)N_NODES * 64)
                  + (size_t)half * ((size_t)N_HALF * 64);
    unsigned fo = fp * 8u;
    int rs = rowstart[n];
    int L = lens[n];
    int c0 = L & 0xffff;
    int start = half ? (rs + ((c0 + 3) & ~3)) : rs;
    int c = half ? (L >> 16) : c0;
    h4v a0 = {(_Float16)0.f, (_Float16)0.f, (_Float16)0.f, (_Float16)0.f};
    h4v a1 = a0, a2 = a0, a3 = a0;
    const unsigned long long* Q = (const unsigned long long*)csr;
    int q0 = start >> 2;
    int nq = c >> 2;
#define ROW1(idx) (*(const h4v*)(T + (unsigned)(idx) * 64u + fo))
    int q = 0;
    unsigned long long ea = 0ull, eb = 0ull;
    if (q + 2 <= nq) { ea = Q[q0]; eb = Q[q0 + 1]; }
    while (q + 2 <= nq) {
        unsigned long long ca = ea, cb = eb;
        q += 2;
        if (q + 2 <= nq) { ea = Q[q0 + q]; eb = Q[q0 + q + 1]; }
        h4v t0 = ROW1(ca & 0xffffu);
        h4v t1 = ROW1((ca >> 16) & 0xffffu);
        h4v t2 = ROW1((ca >> 32) & 0xffffu);
        h4v t3 = ROW1(ca >> 48);
        h4v t4 = ROW1(cb & 0xffffu);
        h4v t5 = ROW1((cb >> 16) & 0xffffu);
        h4v t6 = ROW1((cb >> 32) & 0xffffu);
        h4v t7 = ROW1(cb >> 48);
        a0 += t0; a1 += t1; a2 += t2; a3 += t3;
        a0 += t4; a1 += t5; a2 += t6; a3 += t7;
    }
    if (q < nq) {
        unsigned long long e = Q[q0 + q];
        a0 += ROW1(e & 0xffffu);
        a1 += ROW1((e >> 16) & 0xffffu);
        a2 += ROW1((e >> 32) & 0xffffu);
        a3 += ROW1(e >> 48);
    }
    for (int j = start + (nq << 2); j < start + c; ++j)
        a0 += ROW1(csr[j]);
    if ((n >= N_HALF) == (half != 0))
        a1 += ROW1(n - half * N_HALF);
#undef ROW1
    float s0 = ((float)a0[0] + (float)a1[0]) + ((float)a2[0] + (float)a3[0]);
    float s1 = ((float)a0[1] + (float)a1[1]) + ((float)a2[1] + (float)a3[1]);
    float s2 = ((float)a0[2] + (float)a1[2]) + ((float)a2[2] + (float)a3[2]);
    float s3 = ((float)a0[3] + (float)a1[3]) + ((float)a2[3] + (float)a3[3]);
    union { __half2 h[2]; float2 f; } u;
    u.h[0] = __floats2half2_rn(s0, s1);
    u.h[1] = __floats2half2_rn(s2, s3);
    __half* dst = (half ? out1b : out1a) + (size_t)n * F_HID + chunk * 32 + fp * 4;
    *(float2*)dst = u.f;
}

// ---- GEMM2: hs2 = (relu(dinv*(pa+pb)+b1) @ W2) * dinv, fp16 ---------------
__global__ __launch_bounds__(256) void k_gemm2(const __half* __restrict__ out1a,
                                               const __half* __restrict__ out1b,
                                               const float* __restrict__ W2,
                                               const float* __restrict__ dinv,
                                               const float* __restrict__ b1,
                                               __half* __restrict__ hs2) {
    __shared__ float ws[F_HID * F_OUT];
    __shared__ float b1s[F_HID];
    int t = threadIdx.x;
    ((float4*)ws)[t] = ((const float4*)W2)[t];
    if (t < 16) ((float4*)b1s)[t] = ((const float4*)b1)[t];
    __syncthreads();
    int tid = blockIdx.x * 256 + t;
    int n = tid >> 2;
    if (n >= N_NODES) return;
    int cq = (tid & 3) << 2;
    float dv = dinv[n];
    const h2v* A = (const h2v*)(out1a + (size_t)n * F_HID);
    const h2v* B = (const h2v*)(out1b + (size_t)n * F_HID);
    float4 acc = make_float4(0.f, 0.f, 0.f, 0.f);
#pragma unroll 4
    for (int k4 = 0; k4 < 16; ++k4) {
        h2v pa0 = A[k4 * 2], pa1 = A[k4 * 2 + 1];
        h2v pb0 = B[k4 * 2], pb1 = B[k4 * 2 + 1];
        float h0 = fmaxf(dv * ((float)pa0.x + (float)pb0.x) + b1s[k4 * 4 + 0], 0.f);
        float h1 = fmaxf(dv * ((float)pa0.y + (float)pb0.y) + b1s[k4 * 4 + 1], 0.f);
        float h2 = fmaxf(dv * ((float)pa1.x + (float)pb1.x) + b1s[k4 * 4 + 2], 0.f);
        float h3 = fmaxf(dv * ((float)pa1.y + (float)pb1.y) + b1s[k4 * 4 + 3], 0.f);
        float4 w0 = *(const float4*)(ws + (k4 * 4 + 0) * F_OUT + cq);
        float4 w1 = *(const float4*)(ws + (k4 * 4 + 1) * F_OUT + cq);
        float4 w2 = *(const float4*)(ws + (k4 * 4 + 2) * F_OUT + cq);
        float4 w3 = *(const float4*)(ws + (k4 * 4 + 3) * F_OUT + cq);
        acc.x += h0 * w0.x + h1 * w1.x + h2 * w2.x + h3 * w3.x;
        acc.y += h0 * w0.y + h1 * w1.y + h2 * w2.y + h3 * w3.y;
        acc.z += h0 * w0.z + h1 * w1.z + h2 * w2.z + h3 * w3.z;
        acc.w += h0 * w0.w + h1 * w1.w + h2 * w2.w + h3 * w3.w;
    }
    union { __half2 h2x[2]; float2 f; } u;
    u.h2x[0] = __floats2half2_rn(acc.x * dv, acc.y * dv);
    u.h2x[1] = __floats2half2_rn(acc.z * dv, acc.w * dv);
    *(float2*)(hs2 + (size_t)n * F_OUT + cq) = u.f;
}

// ---- aggregate layer 2: single pass (3.2MB table L2-wide), split sub-rows --
__global__ __launch_bounds__(128) void k_agg2(const __half* __restrict__ hs2,
                                              const unsigned short* __restrict__ csr,
                                              const int* __restrict__ rowstart,
                                              const int* __restrict__ lens,
                                              const float* __restrict__ dinv,
                                              const float* __restrict__ b2,
                                              float* __restrict__ out) {
    int w = threadIdx.x >> 6, lane = threadIdx.x & 63;
    int slot = lane >> 2, fp = lane & 3;
    int n = blockIdx.x * 32 + w * 16 + slot;   // grid = 3125, exact
    unsigned fo = fp * 8u;
    int rs = rowstart[n];
    int L = lens[n];
    int c0 = L & 0xffff, c1 = L >> 16;
    const unsigned long long* Q = (const unsigned long long*)csr;
    h4v a0 = {(_Float16)0.f, (_Float16)0.f, (_Float16)0.f, (_Float16)0.f};
    h4v a1 = a0, a2 = a0, a3 = a0;
#pragma unroll
    for (int half = 0; half < 2; ++half) {
        const char* T = (const char*)hs2 + (size_t)half * ((size_t)N_HALF * 32);
        int start = half ? (rs + ((c0 + 3) & ~3)) : rs;
        int c = half ? c1 : c0;
        int q0 = start >> 2;
        int nq = c >> 2;
#define ROW2(idx) (*(const h4v*)(T + (unsigned)(idx) * 32u + fo))
        int q = 0;
        unsigned long long ea = 0ull, eb = 0ull;
        if (q + 2 <= nq) { ea = Q[q0]; eb = Q[q0 + 1]; }
        while (q + 2 <= nq) {
            unsigned long long ca = ea, cb = eb;
            q += 2;
            if (q + 2 <= nq) { ea = Q[q0 + q]; eb = Q[q0 + q + 1]; }
            h4v t0 = ROW2(ca & 0xffffu);
            h4v t1 = ROW2((ca >> 16) & 0xffffu);
            h4v t2 = ROW2((ca >> 32) & 0xffffu);
            h4v t3 = ROW2(ca >> 48);
            h4v t4 = ROW2(cb & 0xffffu);
            h4v t5 = ROW2((cb >> 16) & 0xffffu);
            h4v t6 = ROW2((cb >> 32) & 0xffffu);
            h4v t7 = ROW2(cb >> 48);
            a0 += t0; a1 += t1; a2 += t2; a3 += t3;
            a0 += t4; a1 += t5; a2 += t6; a3 += t7;
        }
        if (q < nq) {
            unsigned long long e = Q[q0 + q];
            a0 += ROW2(e & 0xffffu);
            a1 += ROW2((e >> 16) & 0xffffu);
            a2 += ROW2((e >> 32) & 0xffffu);
            a3 += ROW2(e >> 48);
        }
        for (int j = start + (nq << 2); j < start + c; ++j)
            a0 += ROW2(csr[j]);
#undef ROW2
    }
    // self
    a1 += *(const h4v*)((const char*)hs2 + (unsigned)n * 32u + fo);
    float dv = dinv[n];
    int fb = fp * 4;
    float s0 = ((float)a0[0] + (float)a1[0]) + ((float)a2[0] + (float)a3[0]);
    float s1 = ((float)a0[1] + (float)a1[1]) + ((float)a2[1] + (float)a3[1]);
    float s2 = ((float)a0[2] + (float)a1[2]) + ((float)a2[2] + (float)a3[2]);
    float s3 = ((float)a0[3] + (float)a1[3]) + ((float)a2[3] + (float)a3[3]);
    float ox0 = dv * s0 + b2[fb + 0];
    float ox1 = dv * s1 + b2[fb + 1];
    float ox2 = dv * s2 + b2[fb + 2];
    float ox3 = dv * s3 + b2[fb + 3];
    float4* dst = (float4*)(out + (size_t)n * F_OUT + fb);
    *dst = make_float4(ox0, ox1, ox2, ox3);
}

extern "C" void kernel_launch(void* const* d_in, const int* in_sizes, int n_in,
                              void* d_out, int out_size, void* d_ws, size_t ws_size,
                              hipStream_t stream) {
    const float* x  = (const float*)d_in[0];
    const void*  ei = d_in[1];
    const float* W1 = (const float*)d_in[2];
    const float* b1 = (const float*)d_in[3];
    const float* W2 = (const float*)d_in[4];
    const float* b2 = (const float*)d_in[5];
    float* out = (float*)d_out;

    char* ws = (char*)d_ws;
    int*            rowstart = (int*)(ws + OFF_RS);
    int*            lens     = (int*)(ws + OFF_LEN);
    float*          dinv     = (float*)(ws + OFF_DINV);
    int*            gcnt     = (int*)(ws + OFF_GCNT);
    unsigned short* csr      = (unsigned short*)(ws + OFF_CSR);
    __half*         hs1      = (__half*)(ws + OFF_HS1);
    __half*         out1a    = (__half*)(ws + OFF_OUT1A);
    __half*         out1b    = (__half*)(ws + OFF_OUT1B);
    __half*         hs2      = (__half*)(ws + OFF_HS2);
    unsigned*       pairs    = (unsigned*)(ws + OFF_PAIRS);

    // edge prep: bucket partition (single edge read) + fused count/scan/place
    (void)hipMemsetAsync(gcnt, 0, NBUCK * sizeof(int), stream);
    k_partition<<<NBLK_P, 256, 0, stream>>>(ei, gcnt, pairs);
    k_build    <<<NBUCK, 512, 0, stream>>>(pairs, gcnt, rowstart, lens, dinv, csr);

    // GCN layers
    k_gemm1<<<G1_BLOCKS, 256, 0, stream>>>(x, W1, dinv, hs1);
    k_agg1 <<<12500, 256, 0, stream>>>(hs1, csr, rowstart, lens, out1a, out1b);
    k_gemm2<<<(N_NODES * 4 + 255) / 256, 256, 0, stream>>>(out1a, out1b, W2, dinv, b1, hs2);
    k_agg2 <<<3125, 128, 0, stream>>>(hs2, csr, rowstart, lens, dinv, b2, out);
}

// Round 13
// 247.792 us; speedup vs baseline: 1.2172x; 1.0268x over previous
//
#include <hip/hip_runtime.h>
#include <hip/hip_fp16.h>
#include <stdint.h>

#define N_NODES   100000
#define N_HALF    50000
#define N_EDGES   3200000
#define F_IN      128
#define F_HID     64
#define F_OUT     16

typedef _Float16 h2v __attribute__((ext_vector_type(2)));
typedef _Float16 h4v __attribute__((ext_vector_type(4)));
typedef _Float16 h8v __attribute__((ext_vector_type(8)));
typedef float    f4v __attribute__((ext_vector_type(4)));

// bucket params: 128-dst buckets
#define BSHIFT    7
#define BK        128                  // dst nodes per bucket
#define NBUCK     782                  // ceil(100000 / 128)
// partition: NBLK_P x NBUCK x 64B = scatter write-sector amplification
// (R11 measured: 1600x782 -> 83MB HBM writes for 12.8MB of pairs).
// 400x782x64 = 20MB. Stash packed to 6B/edge so CHUNK=8000 fits LDS.
#define NBLK_P    400
#define CHUNK_E   (N_EDGES / NBLK_P)   // 8000 edges per block
// bucket capacity: mean raw 4092, sigma ~64. 4992 = +14 sigma.
#define PSTRIDE   4992

// gemm1: 64-node block, 4 waves, mfma_f32_16x16x32_f16
#define G1_TM     64
#define G1_BLOCKS ((N_NODES + G1_TM - 1) / G1_TM)   // 1563

// ---- workspace layout (bytes) ----
#define OFF_RS       0                 // int[N]   rowstart
#define OFF_LEN      400000            // int[N]   c0 | c1<<16
#define OFF_DINV     800000            // float[N]
#define OFF_GCNT     1200000           // int[NBUCK]
#define OFF_CSR      1203200           // u16[NBUCK*PSTRIDE] = 7,807,488 B
#define OFF_HS1      9010688           // half[2][N][32] = 12,800,000 B (64B-aligned!)
#define OFF_OUT1A    21810688          // half[N][64] partials (64B-aligned - R10: saved 9us in agg1)
#define OFF_OUT1B    34610688          // half[N][64] partials
#define OFF_HS2      47410688          // half[N][16]
#define OFF_PAIRS    OFF_OUT1A         // uint[NBUCK*PSTRIDE] = 15,614,976 B, aliases out1a/b
// total 50,610,688 bytes

// ---- pass 1: partition edges into fixed-capacity bucket regions ------------
// Single edge read; (pair,bucket) stashed in LDS (6B/edge) during histogram,
// scattered from LDS after a per-bucket global reservation.
// Write traffic = NBLK_P x NBUCK x 64B sector-touches (R11's lesson) -> 20MB.
// 512 threads (R13): grid 400 x 54KB LDS capped residency at 6.25 waves/CU
// with 256 threads -- same latency-starvation class as R7-gemm1/R9-build.
// Doubling threads doubles waves/CU (12.5) at constant write-amp.
// __launch_bounds__ guard: R4 showed the allocator can go to 8 VGPRs and
// serialize all memory ops if allowed to chase occupancy.
__global__ __launch_bounds__(512, 2) void k_partition(const void* __restrict__ ei,
                                                      int* __restrict__ gcnt,
                                                      unsigned* __restrict__ pairs) {
    __shared__ unsigned stp[CHUNK_E];        // 32,000 B packed pair
    __shared__ unsigned short stb[CHUNK_E];  // 16,000 B bucket id
    __shared__ int h[NBUCK];                 //  3,128 B
    __shared__ int cur[NBUCK];               //  3,128 B   total 54,256 B
    __shared__ int is64s;
    int t = threadIdx.x;
    if (t < 64) {
        const unsigned* u = (const unsigned*)ei;
        unsigned lo = u[2 * t], hi = u[2 * t + 1];
        int bad = (hi != 0u || lo >= 100000u) ? 1 : 0;
        unsigned long long mask = __ballot(bad);
        if (t == 0) is64s = (mask == 0ull);
    }
    for (int i = t; i < NBUCK; i += 512) h[i] = 0;
    __syncthreads();
    int shift = 2 + is64s;
    const char* sp = (const char*)ei;
    const char* dp = sp + ((size_t)N_EDGES << shift);
#define LD_IDX(p, e) __builtin_nontemporal_load((const unsigned*)((p) + ((size_t)(e) << shift)))
    int base = blockIdx.x * CHUNK_E;
    int i = t;
    for (; i + 1536 < CHUNK_E; i += 2048) {
        int e0 = base + i, e1 = e0 + 512, e2 = e0 + 1024, e3 = e0 + 1536;
        unsigned s0 = LD_IDX(sp, e0), s1 = LD_IDX(sp, e1);
        unsigned s2 = LD_IDX(sp, e2), s3 = LD_IDX(sp, e3);
        unsigned d0 = LD_IDX(dp, e0), d1 = LD_IDX(dp, e1);
        unsigned d2 = LD_IDX(dp, e2), d3 = LD_IDX(dp, e3);
        stp[i]        = (s0 << BSHIFT) | (d0 & (BK - 1u));
        stp[i + 512]  = (s1 << BSHIFT) | (d1 & (BK - 1u));
        stp[i + 1024] = (s2 << BSHIFT) | (d2 & (BK - 1u));
        stp[i + 1536] = (s3 << BSHIFT) | (d3 & (BK - 1u));
        stb[i]        = (unsigned short)(d0 >> BSHIFT);
        stb[i + 512]  = (unsigned short)(d1 >> BSHIFT);
        stb[i + 1024] = (unsigned short)(d2 >> BSHIFT);
        stb[i + 1536] = (unsigned short)(d3 >> BSHIFT);
        atomicAdd(&h[d0 >> BSHIFT], 1);
        atomicAdd(&h[d1 >> BSHIFT], 1);
        atomicAdd(&h[d2 >> BSHIFT], 1);
        atomicAdd(&h[d3 >> BSHIFT], 1);
    }
    for (; i < CHUNK_E; i += 512) {
        unsigned s = LD_IDX(sp, base + i);
        unsigned d = LD_IDX(dp, base + i);
        stp[i] = (s << BSHIFT) | (d & (BK - 1u));
        stb[i] = (unsigned short)(d >> BSHIFT);
        atomicAdd(&h[d >> BSHIFT], 1);
    }
#undef LD_IDX
    __syncthreads();
    for (int j = t; j < NBUCK; j += 512) {
        int c = h[j];
        cur[j] = c ? atomicAdd(&gcnt[j], c) : 0;
    }
    __syncthreads();
    i = t;
    for (; i + 1536 < CHUNK_E; i += 2048) {
        unsigned p0v = stp[i],        p1v = stp[i + 512];
        unsigned p2v = stp[i + 1024], p3v = stp[i + 1536];
        int b0 = stb[i], b1 = stb[i + 512], b2 = stb[i + 1024], b3 = stb[i + 1536];
        int p0 = atomicAdd(&cur[b0], 1);
        int p1 = atomicAdd(&cur[b1], 1);
        int p2 = atomicAdd(&cur[b2], 1);
        int p3 = atomicAdd(&cur[b3], 1);
        if (p0 < PSTRIDE) pairs[b0 * PSTRIDE + p0] = p0v;
        if (p1 < PSTRIDE) pairs[b1 * PSTRIDE + p1] = p1v;
        if (p2 < PSTRIDE) pairs[b2 * PSTRIDE + p2] = p2v;
        if (p3 < PSTRIDE) pairs[b3 * PSTRIDE + p3] = p3v;
    }
    for (; i < CHUNK_E; i += 512) {
        int b = stb[i];
        int p = atomicAdd(&cur[b], 1);
        if (p < PSTRIDE) pairs[b * PSTRIDE + p] = stp[i];
    }
}

// ---- pass 2: per-bucket count/scan/place, split by src-half ----------------
// Per node: sub-row 0 (src<50000) then sub-row 1, each start 4-entry aligned.
// Entries u16 half-local src. Bucket pairs stashed in LDS during count pass;
// csr image streamed out as coalesced 16B stores. LDS 32.5KB, grid 782=3/CU.
__global__ __launch_bounds__(512) void k_build(const unsigned* __restrict__ pairs,
                                               const int* __restrict__ gcnt,
                                               int* __restrict__ rowstart,
                                               int* __restrict__ lens,
                                               float* __restrict__ dinv,
                                               unsigned short* __restrict__ csr) {
    __shared__ unsigned prS[PSTRIDE];            // 19,968 B
    __shared__ unsigned short csrS[PSTRIDE];     //  9,984 B
    __shared__ int c0S[BK], c1S[BK], scanS[BK], pos0[BK], pos1[BK];
    __shared__ int totpadS;
    int b = blockIdx.x, t = threadIdx.x;
    if (t < BK) { c0S[t] = 0; c1S[t] = 0; }
    __syncthreads();
    int tot = gcnt[b]; if (tot > PSTRIDE) tot = PSTRIDE;
    int base = b * PSTRIDE;
    for (int i = t; i < tot; i += 512) {
        unsigned pr = __builtin_nontemporal_load(pairs + base + i);
        prS[i] = pr;
        if ((pr >> BSHIFT) < (unsigned)N_HALF) atomicAdd(&c0S[pr & (BK - 1u)], 1);
        else                                   atomicAdd(&c1S[pr & (BK - 1u)], 1);
    }
    __syncthreads();
    int tpad = 0, p0a = 0;
    if (t < BK) {
        p0a = (c0S[t] + 3) & ~3;
        tpad = p0a + ((c1S[t] + 3) & ~3);
        scanS[t] = tpad;
    }
    __syncthreads();
    for (int off = 1; off < BK; off <<= 1) {
        int add = 0;
        if (t < BK && t >= off) add = scanS[t - off];
        __syncthreads();
        if (t < BK) scanS[t] += add;
        __syncthreads();
    }
    if (t < BK) {
        int rs = scanS[t] - tpad;          // exclusive scan, LOCAL, 4-aligned
        pos0[t] = rs;
        pos1[t] = rs + p0a;
        int d = (b << BSHIFT) + t;
        if (d < N_NODES) {
            rowstart[d] = base + rs;
            lens[d] = c0S[t] | (c1S[t] << 16);
            dinv[d] = rsqrtf((float)(c0S[t] + c1S[t]) + 1.0f);
        }
        if (t == BK - 1) totpadS = scanS[BK - 1];
    }
    __syncthreads();
    for (int i = t; i < tot; i += 512) {
        unsigned pr = prS[i];
        unsigned s = pr >> BSHIFT;
        int d = pr & (BK - 1u);
        if (s < (unsigned)N_HALF) {
            int p = atomicAdd(&pos0[d], 1);
            csrS[p] = (unsigned short)s;
        } else {
            int p = atomicAdd(&pos1[d], 1);
            csrS[p] = (unsigned short)(s - N_HALF);
        }
    }
    __syncthreads();
    int nchunk = (totpadS + 7) >> 3;       // 8 u16 per 16B chunk
    uint4* dst = (uint4*)(csr + base);     // base*2 = b*9984, 16B-multiple
    const uint4* srcp = (const uint4*)csrS;
    for (int i = t; i < nchunk; i += 512) dst[i] = srcp[i];
}

// ---- GEMM1 (MFMA fp16-in/fp32-acc): hs1[chunk32][node][32] = (x@W1)*dinv ---
__global__ __launch_bounds__(256, 4) void k_gemm1(const float* __restrict__ x,
                                                  const float* __restrict__ W1,
                                                  const float* __restrict__ dinv,
                                                  __half* __restrict__ hs1) {
    __shared__ _Float16 W1s[F_IN * F_HID];   // 16 KB, fragment-order
    int t = threadIdx.x;
    for (int idx = t; idx < F_IN * F_HID; idx += 256) {
        int k = idx >> 6, n = idx & 63;
        float v = W1[idx];
        int kc = k >> 5, ko = (k >> 3) & 3, j = k & 7;
        int nt = n >> 4, c = n & 15;
        W1s[((kc * 4 + ko) * 4 + nt) * 128 + c * 8 + j] = (_Float16)v;
    }
    __syncthreads();
    int w = t >> 6, l = t & 63;
    int lm = l & 15, lk = l >> 4;
    int nblock = blockIdx.x * G1_TM;
    int anode = nblock + w * 16 + lm;
    int anodec = anode < N_NODES ? anode : N_NODES - 1;
    f4v acc[4] = {};
    const h8v* Bp = (const h8v*)W1s;
#pragma unroll
    for (int kc = 0; kc < 4; ++kc) {
        const f4v* src = (const f4v*)(x + (size_t)anodec * F_IN + kc * 32 + lk * 8);
        f4v v0 = __builtin_nontemporal_load(src);
        f4v v1 = __builtin_nontemporal_load(src + 1);
        h8v a;
#pragma unroll
        for (int i = 0; i < 4; ++i) {
            a[i]     = (_Float16)v0[i];
            a[i + 4] = (_Float16)v1[i];
        }
#pragma unroll
        for (int nt = 0; nt < 4; ++nt) {
            h8v b = Bp[((kc * 4 + lk) * 4 + nt) * 16 + lm];
            acc[nt] = __builtin_amdgcn_mfma_f32_16x16x32_f16(a, b, acc[nt], 0, 0, 0);
        }
    }
#pragma unroll
    for (int r = 0; r < 4; ++r) {
        int node = nblock + w * 16 + lk * 4 + r;
        if (node < N_NODES) {
            float dv = dinv[node];
#pragma unroll
            for (int nt = 0; nt < 4; ++nt) {
                float val = acc[nt][r] * dv;
                hs1[((size_t)(nt >> 1) * N_NODES + node) * 32 + (nt & 1) * 16 + lm] =
                    __float2half(val);
            }
        }
    }
}

// ---- aggregate layer 1: 4 XCD-pinned (chunk x src-half) passes -------------
// Rate = per-CU L1 miss-parallelism wall (~0.19 sectors/cy/CU: ~32 in flight
// x ~175cy L2 latency). 64B-aligned out rows (R10) cut WRITE RMW: 65.8->56.4.
__global__ __launch_bounds__(256) void k_agg1(const __half* __restrict__ hs1,
                                              const unsigned short* __restrict__ csr,
                                              const int* __restrict__ rowstart,
                                              const int* __restrict__ lens,
                                              __half* __restrict__ out1a,
                                              __half* __restrict__ out1b) {
    int bid = blockIdx.x;            // grid = 12500
    int combo = bid & 3;
    int chunk = combo & 1, half = combo >> 1;
    int nb = bid >> 2;               // 0..3124
    int w = threadIdx.x >> 6, lane = threadIdx.x & 63;
    int slot = lane >> 3, fp = lane & 7;
    int n = nb * 32 + w * 8 + slot;  // 3125*32 = 100000 exact
    const char* T = (const char*)hs1
                  + (size_t)chunk * ((size_t)N_NODES * 64)
                  + (size_t)half * ((size_t)N_HALF * 64);
    unsigned fo = fp * 8u;
    int rs = rowstart[n];
    int L = lens[n];
    int c0 = L & 0xffff;
    int start = half ? (rs + ((c0 + 3) & ~3)) : rs;
    int c = half ? (L >> 16) : c0;
    h4v a0 = {(_Float16)0.f, (_Float16)0.f, (_Float16)0.f, (_Float16)0.f};
    h4v a1 = a0, a2 = a0, a3 = a0;
    const unsigned long long* Q = (const unsigned long long*)csr;
    int q0 = start >> 2;
    int nq = c >> 2;
#define ROW1(idx) (*(const h4v*)(T + (unsigned)(idx) * 64u + fo))
    int q = 0;
    unsigned long long ea = 0ull, eb = 0ull;
    if (q + 2 <= nq) { ea = Q[q0]; eb = Q[q0 + 1]; }
    while (q + 2 <= nq) {
        unsigned long long ca = ea, cb = eb;
        q += 2;
        if (q + 2 <= nq) { ea = Q[q0 + q]; eb = Q[q0 + q + 1]; }
        h4v t0 = ROW1(ca & 0xffffu);
        h4v t1 = ROW1((ca >> 16) & 0xffffu);
        h4v t2 = ROW1((ca >> 32) & 0xffffu);
        h4v t3 = ROW1(ca >> 48);
        h4v t4 = ROW1(cb & 0xffffu);
        h4v t5 = ROW1((cb >> 16) & 0xffffu);
        h4v t6 = ROW1((cb >> 32) & 0xffffu);
        h4v t7 = ROW1(cb >> 48);
        a0 += t0; a1 += t1; a2 += t2; a3 += t3;
        a0 += t4; a1 += t5; a2 += t6; a3 += t7;
    }
    if (q < nq) {
        unsigned long long e = Q[q0 + q];
        a0 += ROW1(e & 0xffffu);
        a1 += ROW1((e >> 16) & 0xffffu);
        a2 += ROW1((e >> 32) & 0xffffu);
        a3 += ROW1(e >> 48);
    }
    for (int j = start + (nq << 2); j < start + c; ++j)
        a0 += ROW1(csr[j]);
    if ((n >= N_HALF) == (half != 0))
        a1 += ROW1(n - half * N_HALF);
#undef ROW1
    float s0 = ((float)a0[0] + (float)a1[0]) + ((float)a2[0] + (float)a3[0]);
    float s1 = ((float)a0[1] + (float)a1[1]) + ((float)a2[1] + (float)a3[1]);
    float s2 = ((float)a0[2] + (float)a1[2]) + ((float)a2[2] + (float)a3[2]);
    float s3 = ((float)a0[3] + (float)a1[3]) + ((float)a2[3] + (float)a3[3]);
    union { __half2 h[2]; float2 f; } u;
    u.h[0] = __floats2half2_rn(s0, s1);
    u.h[1] = __floats2half2_rn(s2, s3);
    __half* dst = (half ? out1b : out1a) + (size_t)n * F_HID + chunk * 32 + fp * 4;
    *(float2*)dst = u.f;
}

// ---- GEMM2: hs2 = (relu(dinv*(pa+pb)+b1) @ W2) * dinv, fp16 ---------------
__global__ __launch_bounds__(256) void k_gemm2(const __half* __restrict__ out1a,
                                               const __half* __restrict__ out1b,
                                               const float* __restrict__ W2,
                                               const float* __restrict__ dinv,
                                               const float* __restrict__ b1,
                                               __half* __restrict__ hs2) {
    __shared__ float ws[F_HID * F_OUT];
    __shared__ float b1s[F_HID];
    int t = threadIdx.x;
    ((float4*)ws)[t] = ((const float4*)W2)[t];
    if (t < 16) ((float4*)b1s)[t] = ((const float4*)b1)[t];
    __syncthreads();
    int tid = blockIdx.x * 256 + t;
    int n = tid >> 2;
    if (n >= N_NODES) return;
    int cq = (tid & 3) << 2;
    float dv = dinv[n];
    const h2v* A = (const h2v*)(out1a + (size_t)n * F_HID);
    const h2v* B = (const h2v*)(out1b + (size_t)n * F_HID);
    float4 acc = make_float4(0.f, 0.f, 0.f, 0.f);
#pragma unroll 4
    for (int k4 = 0; k4 < 16; ++k4) {
        h2v pa0 = A[k4 * 2], pa1 = A[k4 * 2 + 1];
        h2v pb0 = B[k4 * 2], pb1 = B[k4 * 2 + 1];
        float h0 = fmaxf(dv * ((float)pa0.x + (float)pb0.x) + b1s[k4 * 4 + 0], 0.f);
        float h1 = fmaxf(dv * ((float)pa0.y + (float)pb0.y) + b1s[k4 * 4 + 1], 0.f);
        float h2 = fmaxf(dv * ((float)pa1.x + (float)pb1.x) + b1s[k4 * 4 + 2], 0.f);
        float h3 = fmaxf(dv * ((float)pa1.y + (float)pb1.y) + b1s[k4 * 4 + 3], 0.f);
        float4 w0 = *(const float4*)(ws + (k4 * 4 + 0) * F_OUT + cq);
        float4 w1 = *(const float4*)(ws + (k4 * 4 + 1) * F_OUT + cq);
        float4 w2 = *(const float4*)(ws + (k4 * 4 + 2) * F_OUT + cq);
        float4 w3 = *(const float4*)(ws + (k4 * 4 + 3) * F_OUT + cq);
        acc.x += h0 * w0.x + h1 * w1.x + h2 * w2.x + h3 * w3.x;
        acc.y += h0 * w0.y + h1 * w1.y + h2 * w2.y + h3 * w3.y;
        acc.z += h0 * w0.z + h1 * w1.z + h2 * w2.z + h3 * w3.z;
        acc.w += h0 * w0.w + h1 * w1.w + h2 * w2.w + h3 * w3.w;
    }
    union { __half2 h2x[2]; float2 f; } u;
    u.h2x[0] = __floats2half2_rn(acc.x * dv, acc.y * dv);
    u.h2x[1] = __floats2half2_rn(acc.z * dv, acc.w * dv);
    *(float2*)(hs2 + (size_t)n * F_OUT + cq) = u.f;
}

// ---- aggregate layer 2: single pass (3.2MB table L2-wide), split sub-rows --
__global__ __launch_bounds__(128) void k_agg2(const __half* __restrict__ hs2,
                                              const unsigned short* __restrict__ csr,
                                              const int* __restrict__ rowstart,
                                              const int* __restrict__ lens,
                                              const float* __restrict__ dinv,
                                              const float* __restrict__ b2,
                                              float* __restrict__ out) {
    int w = threadIdx.x >> 6, lane = threadIdx.x & 63;
    int slot = lane >> 2, fp = lane & 3;
    int n = blockIdx.x * 32 + w * 16 + slot;   // grid = 3125, exact
    unsigned fo = fp * 8u;
    int rs = rowstart[n];
    int L = lens[n];
    int c0 = L & 0xffff, c1 = L >> 16;
    const unsigned long long* Q = (const unsigned long long*)csr;
    h4v a0 = {(_Float16)0.f, (_Float16)0.f, (_Float16)0.f, (_Float16)0.f};
    h4v a1 = a0, a2 = a0, a3 = a0;
#pragma unroll
    for (int half = 0; half < 2; ++half) {
        const char* T = (const char*)hs2 + (size_t)half * ((size_t)N_HALF * 32);
        int start = half ? (rs + ((c0 + 3) & ~3)) : rs;
        int c = half ? c1 : c0;
        int q0 = start >> 2;
        int nq = c >> 2;
#define ROW2(idx) (*(const h4v*)(T + (unsigned)(idx) * 32u + fo))
        int q = 0;
        unsigned long long ea = 0ull, eb = 0ull;
        if (q + 2 <= nq) { ea = Q[q0]; eb = Q[q0 + 1]; }
        while (q + 2 <= nq) {
            unsigned long long ca = ea, cb = eb;
            q += 2;
            if (q + 2 <= nq) { ea = Q[q0 + q]; eb = Q[q0 + q + 1]; }
            h4v t0 = ROW2(ca & 0xffffu);
            h4v t1 = ROW2((ca >> 16) & 0xffffu);
            h4v t2 = ROW2((ca >> 32) & 0xffffu);
            h4v t3 = ROW2(ca >> 48);
            h4v t4 = ROW2(cb & 0xffffu);
            h4v t5 = ROW2((cb >> 16) & 0xffffu);
            h4v t6 = ROW2((cb >> 32) & 0xffffu);
            h4v t7 = ROW2(cb >> 48);
            a0 += t0; a1 += t1; a2 += t2; a3 += t3;
            a0 += t4; a1 += t5; a2 += t6; a3 += t7;
        }
        if (q < nq) {
            unsigned long long e = Q[q0 + q];
            a0 += ROW2(e & 0xffffu);
            a1 += ROW2((e >> 16) & 0xffffu);
            a2 += ROW2((e >> 32) & 0xffffu);
            a3 += ROW2(e >> 48);
        }
        for (int j = start + (nq << 2); j < start + c; ++j)
            a0 += ROW2(csr[j]);
#undef ROW2
    }
    // self
    a1 += *(const h4v*)((const char*)hs2 + (unsigned)n * 32u + fo);
    float dv = dinv[n];
    int fb = fp * 4;
    float s0 = ((float)a0[0] + (float)a1[0]) + ((float)a2[0] + (float)a3[0]);
    float s1 = ((float)a0[1] + (float)a1[1]) + ((float)a2[1] + (float)a3[1]);
    float s2 = ((float)a0[2] + (float)a1[2]) + ((float)a2[2] + (float)a3[2]);
    float s3 = ((float)a0[3] + (float)a1[3]) + ((float)a2[3] + (float)a3[3]);
    float ox0 = dv * s0 + b2[fb + 0];
    float ox1 = dv * s1 + b2[fb + 1];
    float ox2 = dv * s2 + b2[fb + 2];
    float ox3 = dv * s3 + b2[fb + 3];
    float4* dst = (float4*)(out + (size_t)n * F_OUT + fb);
    *dst = make_float4(ox0, ox1, ox2, ox3);
}

extern "C" void kernel_launch(void* const* d_in, const int* in_sizes, int n_in,
                              void* d_out, int out_size, void* d_ws, size_t ws_size,
                              hipStream_t stream) {
    const float* x  = (const float*)d_in[0];
    const void*  ei = d_in[1];
    const float* W1 = (const float*)d_in[2];
    const float* b1 = (const float*)d_in[3];
    const float* W2 = (const float*)d_in[4];
    const float* b2 = (const float*)d_in[5];
    float* out = (float*)d_out;

    char* ws = (char*)d_ws;
    int*            rowstart = (int*)(ws + OFF_RS);
    int*            lens     = (int*)(ws + OFF_LEN);
    float*          dinv     = (float*)(ws + OFF_DINV);
    int*            gcnt     = (int*)(ws + OFF_GCNT);
    unsigned short* csr      = (unsigned short*)(ws + OFF_CSR);
    __half*         hs1      = (__half*)(ws + OFF_HS1);
    __half*         out1a    = (__half*)(ws + OFF_OUT1A);
    __half*         out1b    = (__half*)(ws + OFF_OUT1B);
    __half*         hs2      = (__half*)(ws + OFF_HS2);
    unsigned*       pairs    = (unsigned*)(ws + OFF_PAIRS);

    // edge prep: bucket partition (single edge read) + fused count/scan/place
    (void)hipMemsetAsync(gcnt, 0, NBUCK * sizeof(int), stream);
    k_partition<<<NBLK_P, 512, 0, stream>>>(ei, gcnt, pairs);
    k_build    <<<NBUCK, 512, 0, stream>>>(pairs, gcnt, rowstart, lens, dinv, csr);

    // GCN layers
    k_gemm1<<<G1_BLOCKS, 256, 0, stream>>>(x, W1, dinv, hs1);
    k_agg1 <<<12500, 256, 0, stream>>>(hs1, csr, rowstart, lens, out1a, out1b);
    k_gemm2<<<(N_NODES * 4 + 255) / 256, 256, 0, stream>>>(out1a, out1b, W2, dinv, b1, hs2);
    k_agg2 <<<3125, 128, 0, stream>>>(hs2, csr, rowstart, lens, dinv, b2, out);
}